// Round 11
// baseline (193.569 us; speedup 1.0000x reference)
//
#include <hip/hip_runtime.h>
#include <math.h>

#define PI_F      3.141592653f
#define TWO_PI_F  6.283185306f
#define HALF_PI_F 1.5707963265f
#define IOU_THR_F 0.1f
#define ROUNDS_MAX 16

typedef unsigned long long u64;

__device__ __forceinline__ float limit_period_f(float v) {
    return v - floorf(v / TWO_PI_F + 0.5f) * TWO_PI_F;
}

__device__ __forceinline__ u64 shfl_u64(u64 v, int src) {
    unsigned int lo = (unsigned int)(v & 0xffffffffull);
    unsigned int hi = (unsigned int)(v >> 32);
    lo = __shfl((int)lo, src);
    hi = __shfl((int)hi, src);
    return ((u64)hi << 32) | (u64)lo;
}

// ---------------- Kernel 1: adjacency + (last block) MIS + indices ------------
// adj: thread owns (row i, word w); 64 in-register IoUs vs LDS-staged j-boxes.
// occByte[rb*64+w] = any row in block rb has nonzero word w (single producer).
// Last block (completion counter) runs the whole greedy-MIS with S/R in LDS
// (__syncthreads rounds, no grid barriers), then indices/seedList/nclust.
__global__ __launch_bounds__(1024) void adjmis_kernel(
        const float* __restrict__ boxes,
        u64* __restrict__ adjC,
        unsigned char* __restrict__ occByte,
        int* __restrict__ indices,
        int* __restrict__ seedList,
        int* __restrict__ nclust,
        int* __restrict__ done,
        int n, int words) {
    __shared__ float jS[7][64];
    __shared__ int lastFlag;
    int w = blockIdx.x;
    int tid = threadIdx.x;              // 1024 = 16 waves
    int lane = tid & 63, wv = tid >> 6;
    if (tid < 64) {
        int j = (w << 6) + tid;
        if (j < n) {
            float b0 = boxes[j*7+0], b1 = boxes[j*7+1], b2 = boxes[j*7+2];
            float b3 = boxes[j*7+3], b4 = boxes[j*7+4], b5 = boxes[j*7+5];
            jS[0][tid] = b0 - b5*0.5f;  jS[3][tid] = b0 + b5*0.5f;
            jS[1][tid] = b1 - b4*0.5f;  jS[4][tid] = b1 + b4*0.5f;
            jS[2][tid] = b2 - b3*0.5f;  jS[5][tid] = b2 + b3*0.5f;
            jS[6][tid] = (b5*b4)*b3;
        }
    }
    __syncthreads();
    int i = blockIdx.y * 1024 + tid;
    u64 word = 0ull;
    if (i < n) {
        float b0 = boxes[i*7+0], b1 = boxes[i*7+1], b2 = boxes[i*7+2];
        float b3 = boxes[i*7+3], b4 = boxes[i*7+4], b5 = boxes[i*7+5];
        float lix = b0 - b5*0.5f, hix = b0 + b5*0.5f;
        float liy = b1 - b4*0.5f, hiy = b1 + b4*0.5f;
        float liz = b2 - b3*0.5f, hiz = b2 + b3*0.5f;
        float vi  = (b5*b4)*b3;
        int jmax = n - (w << 6); if (jmax > 64) jmax = 64;
        for (int jj = 0; jj < jmax; ++jj) {
            float ix = fminf(hix, jS[3][jj]) - fmaxf(lix, jS[0][jj]); ix = fmaxf(ix, 0.0f);
            float iy = fminf(hiy, jS[4][jj]) - fmaxf(liy, jS[1][jj]); iy = fmaxf(iy, 0.0f);
            float iz = fminf(hiz, jS[5][jj]) - fmaxf(liz, jS[2][jj]); iz = fmaxf(iz, 0.0f);
            float inter = (ix*iy)*iz;
            float u = fmaxf(vi + jS[6][jj] - inter, 1e-8f);
            bool pred = (inter / u) > IOU_THR_F;
            word |= ((u64)(pred ? 1 : 0)) << jj;
        }
        adjC[(size_t)w * n + i] = word;
    }
    u64 bal = __ballot((i < n) && word != 0ull);
    int rb = blockIdx.y * 16 + wv;
    if (lane == 0 && rb < 64) occByte[rb * 64 + w] = bal ? (unsigned char)1 : (unsigned char)0;
    __syncthreads();
    if (tid == 0) {
        __threadfence();
        int total = gridDim.x * gridDim.y;
        int old = __hip_atomic_fetch_add(done, 1, __ATOMIC_ACQ_REL, __HIP_MEMORY_SCOPE_AGENT);
        lastFlag = (old == total - 1) ? 1 : 0;
    }
    __syncthreads();
    if (!lastFlag) return;
    __threadfence();

    // ---------------- MIS tail (one block, 16 waves, S/R in LDS) --------------
    __shared__ u64 S_lds[64], R_lds[64], occM[64];
    __shared__ int unresolved;
    __shared__ int wsS[64];
    __shared__ int totS;
    if (tid < 64) {
        int base = tid << 6;
        int vb = n - base;
        u64 valid = (vb >= 64) ? ~0ull : ((vb <= 0) ? 0ull : ((1ull << vb) - 1ull));
        S_lds[tid] = 0ull; R_lds[tid] = ~valid;
    }
    for (int rb2 = wv; rb2 < 64; rb2 += 16) {
        unsigned char b = occByte[rb2 * 64 + lane];
        u64 m = __ballot(b != 0);
        if (lane == 0) occM[rb2] = m;
    }
    __syncthreads();
    for (int r = 0; r < ROUNDS_MAX; ++r) {
        if (tid == 0) unresolved = 0;
        __syncthreads();
        for (int k = 0; k < 4; ++k) {            // wave wv owns words 4wv..4wv+3
            int w2 = (wv << 2) + k;
            if (w2 >= words) continue;
            int base = w2 << 6;
            int vb = n - base;
            u64 valid = (vb >= 64) ? ~0ull : ((vb <= 0) ? 0ull : ((1ull << vb) - 1ull));
            u64 Rw = R_lds[w2];
            u64 unknownIn = valid & ~Rw;          // wave-uniform
            if (unknownIn == 0ull) continue;
            int i2 = base + lane;
            u64 sA = 0ull, uA = 0ull;
            u64 occE = occM[w2] & (w2 ? ((1ull << w2) - 1ull) : 0ull);
            while (occE) {
                int e = (int)__ffsll(occE) - 1; occE &= occE - 1;
                u64 row = (i2 < n) ? adjC[(size_t)e * n + i2] : 0ull;
                sA |= row & S_lds[e];
                uA |= row & ~R_lds[e];
            }
            u64 E_seen  = __ballot(sA != 0ull);
            u64 Unk_ext = __ballot(uA != 0ull);
            u64 Adiag = (i2 < n) ? adjC[(size_t)w2 * n + i2] : 0ull;
            // exact in-word greedy over unresolved bits, ascending
            u64 newSeed = S_lds[w2];
            u64 newRes  = Rw;
            u64 pending = unknownIn;
            while (pending) {
                int b = (int)__ffsll(pending) - 1;
                pending &= pending - 1;
                u64 rowb = shfl_u64(Adiag, b);
                u64 below = b ? ((1ull << b) - 1ull) : 0ull;
                u64 earlier = rowb & below;
                u64 bit = 1ull << b;
                bool eSeen = (E_seen >> b) & 1ull;
                bool eUnk  = (Unk_ext >> b) & 1ull;
                if (eSeen || (earlier & newSeed)) {
                    newRes |= bit;                      // nonseed
                } else if (eUnk || (earlier & ~newRes)) {
                    // blocked: unresolved earlier neighbor
                } else {
                    newSeed |= bit; newRes |= bit;      // seed
                }
            }
            if (lane == 0) {
                S_lds[w2] = newSeed; R_lds[w2] = newRes;
                if (newRes != valid) atomicAdd(&unresolved, 1);
            }
        }
        __syncthreads();
        if (unresolved == 0) break;                // uniform
        __syncthreads();
    }
    // seed ranks (wave 0)
    if (tid < 64) {
        u64 s = (tid < words) ? S_lds[tid] : 0ull;
        int pc = (int)__popcll(s);
        int x = pc;
        for (int o = 1; o < 64; o <<= 1) {
            int y = __shfl_up(x, o);
            if (tid >= o) x += y;
        }
        wsS[tid] = x - pc;                        // exclusive scan
        if (tid == 63) totS = x;
    }
    __syncthreads();
    if (tid == 0) *nclust = totS;
    // indices[j] = rank of max-index adjacent seed; also seedList
    for (int j = tid; j < n; j += 1024) {         // lanes consecutive -> coalesced
        int rb2 = j >> 6;
        int best = -1;
        u64 tmp = occM[rb2];
        while (tmp) {
            int w2 = (int)__ffsll(tmp) - 1; tmp &= tmp - 1;
            u64 m = adjC[(size_t)w2 * n + j] & S_lds[w2];
            if (m) best = (w2 << 6) + 63 - (int)__clzll(m);
        }
        int idx = 0;
        if (best >= 0) {
            int w2 = best >> 6, b = best & 63;
            u64 incl = (b >= 63) ? ~0ull : ((2ull << b) - 1ull);
            idx = wsS[w2] + (int)__popcll(S_lds[w2] & incl);  // 1-based cid
        }
        indices[j] = idx;
        int bj = j & 63;
        if ((S_lds[rb2] >> bj) & 1ull) {
            int rank = wsS[rb2] + (int)__popcll(S_lds[rb2] & (bj ? ((1ull << bj) - 1ull) : 0ull)) + 1;
            seedList[rank - 1] = j;
        }
    }
}

// ---------------- Kernel 2: fusion (wave 0) + (last block) finalize -----------
__global__ __launch_bounds__(256) void fusionfinal_kernel(
        const float* __restrict__ boxes,
        const float* __restrict__ scores,
        const int* __restrict__ indices,
        const int* __restrict__ seedListG,
        const int* __restrict__ nclust,
        const u64* __restrict__ adjC,
        float* __restrict__ fused,
        float* __restrict__ sfused,
        int* __restrict__ validArr,
        int* __restrict__ done,
        float* __restrict__ out, int n, int words) {
    int tid = threadIdx.x;        // 256 = 4 waves; fusion on wave 0 only
    int lane = tid & 63, wv = tid >> 6;
    __shared__ unsigned short js[256];
    __shared__ float ms[256];
    __shared__ float ds[256];
    __shared__ int lastFlag;
    int nc = *nclust;
    if (wv == 0) {
        for (int i = blockIdx.x; i < n; i += gridDim.x) {
            int cid = i + 1;
            if (cid > nc) {
                if (lane < 7) fused[i*7+lane] = 0.0f;
                if (lane == 0) { sfused[i] = 0.0f; validArr[i] = 0; }
                continue;
            }
            int s = seedListG[i];
            u64 bits = (lane < words) ? adjC[(size_t)lane * n + s] : 0ull;
            u64 keep = 0ull;
            u64 t = bits;
            while (t) {
                int b = (int)__ffsll(t) - 1;
                t &= t - 1;
                int node = (lane << 6) + b;
                if (indices[node] == cid) keep |= (1ull << b);
            }
            int cnt = __popcll(keep);
            int x = cnt;
            for (int o = 1; o < 64; o <<= 1) {
                int y = __shfl_up(x, o);
                if (lane >= o) x += y;
            }
            int excl = x - cnt;
            int m = __shfl(x, 63);
            int pos = excl;
            t = keep;
            while (t) {
                int b = (int)__ffsll(t) - 1;
                t &= t - 1;
                js[pos++] = (unsigned short)((lane << 6) + b);
            }
            asm volatile("s_waitcnt lgkmcnt(0)" ::: "memory");   // wave-local LDS order
            for (int k = lane; k < m; k += 64) {
                int j = js[k];
                ms[k] = scores[j];
                ds[k] = limit_period_f(boxes[j*7+6]);
            }
            asm volatile("s_waitcnt lgkmcnt(0)" ::: "memory");
            if (lane == 0) {
                if (m == 0) {
                    for (int k = 0; k < 7; ++k) fused[i*7+k] = 0.0f;
                    sfused[i] = 0.0f; validArr[i] = 0;
                } else {
                    float ssum = 0.0f, smax = -1e30f; int kref = 0;
                    for (int k = 0; k < m; ++k) {
                        float sc = ms[k];
                        ssum += sc;
                        if (sc > smax) { smax = sc; kref = k; }
                    }
                    float refdir = ds[kref];
                    float denom = fmaxf(ssum, 1e-12f);
                    float sgt = 0.0f;
                    float cd0=0,cd1=0,cd2=0,cd3=0,cd4=0,cd5=0;
                    for (int k = 0; k < m; ++k) {
                        int j = js[k];
                        float sc = ms[k];
                        float d = fabsf(ds[k] - refdir);
                        if (d > PI_F) d = TWO_PI_F - d;
                        if (d > HALF_PI_F) sgt += sc;
                        float wgt = sc / denom;
                        cd0 += wgt * boxes[j*7+0];
                        cd1 += wgt * boxes[j*7+1];
                        cd2 += wgt * boxes[j*7+2];
                        cd3 += wgt * boxes[j*7+3];
                        cd4 += wgt * boxes[j*7+4];
                        cd5 += wgt * boxes[j*7+5];
                    }
                    float sle = ssum - sgt;
                    bool flipGt = (sgt <= sle);
                    float ssin = 0.0f, scos = 0.0f;
                    for (int k = 0; k < m; ++k) {
                        float sc = ms[k];
                        float dj = ds[k];
                        float d = fabsf(dj - refdir);
                        if (d > PI_F) d = TWO_PI_F - d;
                        bool gt = d > HALF_PI_F;
                        bool flip = flipGt ? gt : !gt;
                        float adj_d = limit_period_f(dj + (flip ? PI_F : 0.0f));
                        float wgt = sc / denom;
                        ssin += sinf(adj_d) * wgt;
                        scos += cosf(adj_d) * wgt;
                    }
                    float theta = atan2f(ssin, scos);
                    for (int k = 1; k < m; ++k) {
                        float key = ms[k]; int p = k - 1;
                        while (p >= 0 && ms[p] < key) { ms[p+1] = ms[p]; --p; }
                        ms[p+1] = key;
                    }
                    float sf = 0.0f;
                    for (int k = 0; k < m; ++k) sf += powf(ms[k], (float)(k+1));
                    sf = fminf(sf, 1.0f);
                    float c_ = cosf(theta), s_ = sinf(theta);
                    float wdim = cd4, ldim = cd5;
                    const float xs[4]  = {0.5f, 0.5f, -0.5f, -0.5f};
                    const float ys_[4] = {-0.5f, 0.5f, 0.5f, -0.5f};
                    bool inr = true;
                    for (int c = 0; c < 4; ++c) {
                        float cx = ldim * xs[c], cy = wdim * ys_[c];
                        float rx = cx*c_ - cy*s_ + cd0;
                        float ry = cx*s_ + cy*c_ + cd1;
                        inr = inr && (rx > -140.8f) && (rx < 140.8f) && (ry > -40.0f) && (ry < 40.0f);
                    }
                    fused[i*7+0]=cd0; fused[i*7+1]=cd1; fused[i*7+2]=cd2;
                    fused[i*7+3]=cd3; fused[i*7+4]=cd4; fused[i*7+5]=cd5;
                    fused[i*7+6]=theta;
                    sfused[i] = sf;
                    validArr[i] = inr ? 1 : 0;
                }
            }
            asm volatile("s_waitcnt lgkmcnt(0)" ::: "memory");
        }
    }
    __syncthreads();
    if (tid == 0) {
        __threadfence();
        int old = __hip_atomic_fetch_add(done, 1, __ATOMIC_ACQ_REL, __HIP_MEMORY_SCOPE_AGENT);
        lastFlag = (old == (int)gridDim.x - 1) ? 1 : 0;
    }
    __syncthreads();
    if (!lastFlag) return;
    __threadfence();

    // ---------------- finalize tail (one block, 256 threads) ------------------
    __shared__ int newidS[4096];
    __shared__ unsigned char validS[4096];
    __shared__ int scanBuf[256];
    int per = (n + 255) >> 8;     // 16 for n=4096
    int base = tid * per;
    int v[16];
    int sum = 0;
    for (int k = 0; k < per && k < 16; ++k) {
        int j = base + k;
        int vv = (j < n) ? validArr[j] : 0;
        v[k] = vv; sum += vv;
    }
    scanBuf[tid] = sum;
    __syncthreads();
    for (int o = 1; o < 256; o <<= 1) {
        int val = scanBuf[tid];
        int add = (tid >= o) ? scanBuf[tid - o] : 0;
        __syncthreads();
        scanBuf[tid] = val + add;
        __syncthreads();
    }
    int run = scanBuf[tid] - sum;
    for (int k = 0; k < per && k < 16; ++k) {
        int j = base + k;
        if (j < n) { run += v[k]; newidS[j] = run; validS[j] = (unsigned char)v[k]; }
    }
    __syncthreads();
    float* boxesO  = out;
    float* scoresO = out + (size_t)7*n;
    float* validO  = out + (size_t)8*n;
    float* idxO    = out + (size_t)9*n;
    for (int j = tid; j < n; j += 256) {
        int vv = validS[j];
        #pragma unroll
        for (int k = 0; k < 7; ++k)
            boxesO[j*7+k] = vv ? fused[j*7+k] : 0.0f;
        scoresO[j] = vv ? sfused[j] : 0.0f;
        validO[j]  = vv ? 1.0f : 0.0f;
        int ind = indices[j];
        int safe = ind - 1; if (safe < 0) safe = 0;
        bool nv = (ind > 0) && (validS[safe] != 0);
        idxO[j] = nv ? (float)newidS[safe] : 0.0f;
    }
}

extern "C" void kernel_launch(void* const* d_in, const int* in_sizes, int n_in,
                              void* d_out, int out_size, void* d_ws, size_t ws_size,
                              hipStream_t stream) {
    const float* boxes  = (const float*)d_in[0];
    const float* scores = (const float*)d_in[1];
    int n = in_sizes[0] / 7;           // 4096
    int words = (n + 63) >> 6;         // 64

    char* ws = (char*)d_ws;
    size_t off = 0;
    u64* adjC = (u64*)(ws + off);
    off += (size_t)n * words * sizeof(u64);
    unsigned char* occByte = (unsigned char*)(ws + off); off += 64 * 64;
    int* seedList = (int*)(ws + off); off += (size_t)n * sizeof(int);
    int* indices  = (int*)(ws + off); off += (size_t)n * sizeof(int);
    float* fused  = (float*)(ws + off); off += (size_t)n * 7 * sizeof(float);
    float* sfused = (float*)(ws + off); off += (size_t)n * sizeof(float);
    int* validArr = (int*)(ws + off); off += (size_t)n * sizeof(int);
    int* nclust   = (int*)(ws + off); off += sizeof(int);
    off = (off + 7) & ~(size_t)7;
    int* done     = (int*)(ws + off); off += 2 * sizeof(int);   // {adj, fusion}

    hipMemsetAsync(done, 0, 2 * sizeof(int), stream);
    dim3 g1(words, (n + 1023) / 1024);
    adjmis_kernel<<<g1, 1024, 0, stream>>>(boxes, adjC, occByte, indices, seedList,
                                           nclust, done, n, words);
    fusionfinal_kernel<<<512, 256, 0, stream>>>(boxes, scores, indices, seedList, nclust,
                                                adjC, fused, sfused, validArr, done + 1,
                                                (float*)d_out, n, words);
}

// Round 12
// 184.227 us; speedup vs baseline: 1.0507x; 1.0507x over previous
//
#include <hip/hip_runtime.h>
#include <math.h>

#define PI_F      3.141592653f
#define TWO_PI_F  6.283185306f
#define HALF_PI_F 1.5707963265f
#define IOU_THR_F 0.1f

typedef unsigned long long u64;

__device__ __forceinline__ float limit_period_f(float v) {
    return v - floorf(v / TWO_PI_F + 0.5f) * TWO_PI_F;
}

__device__ __forceinline__ u64 shfl_u64(u64 v, int src) {
    unsigned int lo = (unsigned int)(v & 0xffffffffull);
    unsigned int hi = (unsigned int)(v >> 32);
    lo = __shfl((int)lo, src);
    hi = __shfl((int)hi, src);
    return ((u64)hi << 32) | (u64)lo;
}

// ---------------- Kernel 1: adjacency + word-occupancy mask (R10) -------------
__global__ void adj_kernel(const float* __restrict__ boxes,
                           u64* __restrict__ adjC, u64* __restrict__ occMask,
                           int n, int words) {
    __shared__ float jS[7][64];
    int w = blockIdx.x;
    int tid = threadIdx.x;              // 256 = 4 waves
    int lane = tid & 63, wv = tid >> 6;
    if (tid < 64) {
        int j = (w << 6) + tid;
        if (j < n) {
            float b0 = boxes[j*7+0], b1 = boxes[j*7+1], b2 = boxes[j*7+2];
            float b3 = boxes[j*7+3], b4 = boxes[j*7+4], b5 = boxes[j*7+5];
            jS[0][tid] = b0 - b5*0.5f;  jS[3][tid] = b0 + b5*0.5f;
            jS[1][tid] = b1 - b4*0.5f;  jS[4][tid] = b1 + b4*0.5f;
            jS[2][tid] = b2 - b3*0.5f;  jS[5][tid] = b2 + b3*0.5f;
            jS[6][tid] = (b5*b4)*b3;
        }
    }
    __syncthreads();
    int i = blockIdx.y * 256 + tid;
    if (i >= n) return;
    float b0 = boxes[i*7+0], b1 = boxes[i*7+1], b2 = boxes[i*7+2];
    float b3 = boxes[i*7+3], b4 = boxes[i*7+4], b5 = boxes[i*7+5];
    float lix = b0 - b5*0.5f, hix = b0 + b5*0.5f;
    float liy = b1 - b4*0.5f, hiy = b1 + b4*0.5f;
    float liz = b2 - b3*0.5f, hiz = b2 + b3*0.5f;
    float vi  = (b5*b4)*b3;
    int jmax = n - (w << 6); if (jmax > 64) jmax = 64;
    u64 word = 0ull;
    for (int jj = 0; jj < jmax; ++jj) {
        float ix = fminf(hix, jS[3][jj]) - fmaxf(lix, jS[0][jj]); ix = fmaxf(ix, 0.0f);
        float iy = fminf(hiy, jS[4][jj]) - fmaxf(liy, jS[1][jj]); iy = fmaxf(iy, 0.0f);
        float iz = fminf(hiz, jS[5][jj]) - fmaxf(liz, jS[2][jj]); iz = fmaxf(iz, 0.0f);
        float inter = (ix*iy)*iz;
        float u = fmaxf(vi + jS[6][jj] - inter, 1e-8f);
        bool pred = (inter / u) > IOU_THR_F;
        word |= ((u64)(pred ? 1 : 0)) << jj;
    }
    adjC[(size_t)w * n + i] = word;
    u64 bal = __ballot(word != 0ull);
    if (lane == 0 && bal)
        atomicOr(&occMask[blockIdx.y * 4 + wv], 1ull << w);
}

// ---------------- Kernel 2: single-pass chained greedy MIS + indices ----------
// Word w depends only on words < w  =>  one ordered pass is exact.
// 8 blocks x 512 thr; wave k of block g owns word 8g+k. Phase A preloads
// diagonal + occ-masked earlier rows (parallel, latency hidden). Phase B:
// block g spins for flag==g, resolves its 8 words in-block (pure ALU),
// publishes S, sets flag=g+1. Then all blocks spin for flag==ngroups and
// compute indices/seedList/nclust in parallel.
__global__ __launch_bounds__(512) void mis_chain_kernel(
        const u64* __restrict__ adjC,
        const u64* __restrict__ occMask,
        u64* __restrict__ S,
        int* __restrict__ indices,
        int* __restrict__ seedList,
        int* __restrict__ nclust,
        int* __restrict__ flag,
        int n, int words, int ngroups) {
    __shared__ u64 S_lds[8];
    __shared__ u64 smS[64];
    __shared__ int wsS[64];
    int g = blockIdx.x;
    int tid = threadIdx.x;              // 512 = 8 waves
    int lane = tid & 63, wv = tid >> 6;
    int gbase = g << 3;
    int w = gbase + wv;
    bool wactive = (w < words);
    int base = w << 6;
    int vb = n - base;
    u64 valid = wactive ? ((vb >= 64) ? ~0ull : ((vb <= 0) ? 0ull : ((1ull << vb) - 1ull))) : 0ull;
    int i = base + lane;

    // ---- Phase A: dependency-free preloads (overlaps across all blocks) ----
    u64 Adiag = (wactive && i < n) ? adjC[(size_t)w * n + i] : 0ull;
    u64 occE = 0ull;
    if (wactive) occE = occMask[w] & (w ? ((1ull << w) - 1ull) : 0ull);
    int e0=-1,e1=-1,e2=-1,e3=-1,e4=-1,e5=-1;
    u64 t = occE;
    if (t) { e0 = (int)__ffsll(t) - 1; t &= t - 1; }
    if (t) { e1 = (int)__ffsll(t) - 1; t &= t - 1; }
    if (t) { e2 = (int)__ffsll(t) - 1; t &= t - 1; }
    if (t) { e3 = (int)__ffsll(t) - 1; t &= t - 1; }
    if (t) { e4 = (int)__ffsll(t) - 1; t &= t - 1; }
    if (t) { e5 = (int)__ffsll(t) - 1; t &= t - 1; }
    u64 rest = t;                        // rarely nonzero; handled at turn
    bool ld = (i < n);
    u64 r0 = (e0 >= 0 && ld) ? adjC[(size_t)e0 * n + i] : 0ull;
    u64 r1 = (e1 >= 0 && ld) ? adjC[(size_t)e1 * n + i] : 0ull;
    u64 r2 = (e2 >= 0 && ld) ? adjC[(size_t)e2 * n + i] : 0ull;
    u64 r3 = (e3 >= 0 && ld) ? adjC[(size_t)e3 * n + i] : 0ull;
    u64 r4 = (e4 >= 0 && ld) ? adjC[(size_t)e4 * n + i] : 0ull;
    u64 r5 = (e5 >= 0 && ld) ? adjC[(size_t)e5 * n + i] : 0ull;

    // ---- Phase B: wait for predecessor groups, then in-block ordered pass ----
    if (tid == 0 && g > 0) {
        while (__hip_atomic_load(flag, __ATOMIC_ACQUIRE, __HIP_MEMORY_SCOPE_AGENT) < g)
            __builtin_amdgcn_s_sleep(2);
    }
    __syncthreads();
    __threadfence();
    for (int k = 0; k < 8; ++k) {
        if (wv == k && wactive) {
            u64 sA = 0ull;
            if (e0 >= 0) { u64 sv = (e0 >= gbase) ? S_lds[e0 - gbase] : __hip_atomic_load(&S[e0], __ATOMIC_RELAXED, __HIP_MEMORY_SCOPE_AGENT); sA |= r0 & sv; }
            if (e1 >= 0) { u64 sv = (e1 >= gbase) ? S_lds[e1 - gbase] : __hip_atomic_load(&S[e1], __ATOMIC_RELAXED, __HIP_MEMORY_SCOPE_AGENT); sA |= r1 & sv; }
            if (e2 >= 0) { u64 sv = (e2 >= gbase) ? S_lds[e2 - gbase] : __hip_atomic_load(&S[e2], __ATOMIC_RELAXED, __HIP_MEMORY_SCOPE_AGENT); sA |= r2 & sv; }
            if (e3 >= 0) { u64 sv = (e3 >= gbase) ? S_lds[e3 - gbase] : __hip_atomic_load(&S[e3], __ATOMIC_RELAXED, __HIP_MEMORY_SCOPE_AGENT); sA |= r3 & sv; }
            if (e4 >= 0) { u64 sv = (e4 >= gbase) ? S_lds[e4 - gbase] : __hip_atomic_load(&S[e4], __ATOMIC_RELAXED, __HIP_MEMORY_SCOPE_AGENT); sA |= r4 & sv; }
            if (e5 >= 0) { u64 sv = (e5 >= gbase) ? S_lds[e5 - gbase] : __hip_atomic_load(&S[e5], __ATOMIC_RELAXED, __HIP_MEMORY_SCOPE_AGENT); sA |= r5 & sv; }
            u64 rr = rest;
            while (rr) {
                int e = (int)__ffsll(rr) - 1; rr &= rr - 1;
                u64 row = ld ? adjC[(size_t)e * n + i] : 0ull;
                u64 sv = (e >= gbase) ? S_lds[e - gbase] : __hip_atomic_load(&S[e], __ATOMIC_RELAXED, __HIP_MEMORY_SCOPE_AGENT);
                sA |= row & sv;
            }
            u64 E_seen = __ballot(sA != 0ull);
            u64 cand = valid & ~E_seen;
            u64 s = 0ull;
            while (cand) {                       // exact in-word ascending greedy
                int b = (int)__ffsll(cand) - 1;
                s |= 1ull << b;
                u64 Ab = shfl_u64(Adiag, b);
                cand &= ~Ab;
                u64 him = (b >= 63) ? 0ull : ~((2ull << b) - 1ull);
                cand &= him;
            }
            if (lane == 0) {
                S_lds[k] = s;
                __hip_atomic_store(&S[w], s, __ATOMIC_RELAXED, __HIP_MEMORY_SCOPE_AGENT);
            }
        }
        __syncthreads();
    }
    if (tid == 0) {
        __threadfence();
        __hip_atomic_store(flag, g + 1, __ATOMIC_RELEASE, __HIP_MEMORY_SCOPE_AGENT);
        while (__hip_atomic_load(flag, __ATOMIC_ACQUIRE, __HIP_MEMORY_SCOPE_AGENT) < ngroups)
            __builtin_amdgcn_s_sleep(2);
    }
    __syncthreads();
    __threadfence();

    // ---- indices / seedList / nclust (all blocks, disjoint j ranges) ----
    if (tid < 64) {
        smS[tid] = (tid < words) ? __hip_atomic_load(&S[tid], __ATOMIC_RELAXED, __HIP_MEMORY_SCOPE_AGENT) : 0ull;
    }
    __syncthreads();
    if (tid < 64) {
        int pc = (int)__popcll(smS[tid]);
        int x = pc;
        for (int o = 1; o < 64; o <<= 1) {
            int y = __shfl_up(x, o);
            if (tid >= o) x += y;
        }
        wsS[tid] = x - pc;                        // exclusive scan
    }
    __syncthreads();
    if (g == 0 && tid == 0) *nclust = wsS[63] + (int)__popcll(smS[63]);
    int stride = ngroups << 9;                    // ngroups * 512
    for (int j = (g << 9) + tid; j < n; j += stride) {
        int rb = j >> 6;
        int best = -1;
        u64 tmp = (rb < 64) ? occMask[rb] : 0ull;
        while (tmp) {
            int w2 = (int)__ffsll(tmp) - 1; tmp &= tmp - 1;
            u64 m = adjC[(size_t)w2 * n + j] & smS[w2];   // coalesced across j
            if (m) best = (w2 << 6) + 63 - (int)__clzll(m);
        }
        int idx = 0;
        if (best >= 0) {
            int w2 = best >> 6, b = best & 63;
            u64 incl = (b >= 63) ? ~0ull : ((2ull << b) - 1ull);
            idx = wsS[w2] + (int)__popcll(smS[w2] & incl);  // 1-based cid
        }
        indices[j] = idx;
        int bj = j & 63;
        if ((smS[rb] >> bj) & 1ull) {
            int rank = wsS[rb] + (int)__popcll(smS[rb] & (bj ? ((1ull << bj) - 1ull) : 0ull)) + 1;
            seedList[rank - 1] = j;
        }
    }
}

// ---------------- Kernel 3: per-cluster fusion (grid-stride, 1 wave/block) ----
__global__ void fusion_kernel(const float* __restrict__ boxes,
                              const float* __restrict__ scores,
                              const int* __restrict__ indices,
                              const int* __restrict__ seedListG,
                              const int* __restrict__ nclust,
                              const u64* __restrict__ adjC,
                              float* __restrict__ fused,
                              float* __restrict__ sfused,
                              int* __restrict__ validArr, int n, int words) {
    int lane = threadIdx.x;       // 64 = 1 wave
    int nc = *nclust;
    __shared__ unsigned short js[256];
    __shared__ float ms[256];
    __shared__ float ds[256];
    for (int i = blockIdx.x; i < n; i += gridDim.x) {
        int cid = i + 1;
        if (cid > nc) {
            if (lane < 7) fused[i*7+lane] = 0.0f;
            if (lane == 0) { sfused[i] = 0.0f; validArr[i] = 0; }
            continue;
        }
        int s = seedListG[i];
        u64 bits = (lane < words) ? adjC[(size_t)lane * n + s] : 0ull;
        // filter: keep only nodes whose final cluster is cid
        u64 keep = 0ull;
        u64 t = bits;
        while (t) {
            int b = (int)__ffsll(t) - 1;
            t &= t - 1;
            int node = (lane << 6) + b;
            if (indices[node] == cid) keep |= (1ull << b);
        }
        int cnt = __popcll(keep);
        int x = cnt;
        for (int o = 1; o < 64; o <<= 1) {
            int y = __shfl_up(x, o);
            if (lane >= o) x += y;
        }
        int excl = x - cnt;
        int m = __shfl(x, 63);
        int pos = excl;
        t = keep;
        while (t) {
            int b = (int)__ffsll(t) - 1;
            t &= t - 1;
            js[pos++] = (unsigned short)((lane << 6) + b);
        }
        __syncthreads();
        for (int k = lane; k < m; k += 64) {
            int j = js[k];
            ms[k] = scores[j];
            ds[k] = limit_period_f(boxes[j*7+6]);
        }
        __syncthreads();
        if (lane == 0) {
            if (m == 0) {
                for (int k = 0; k < 7; ++k) fused[i*7+k] = 0.0f;
                sfused[i] = 0.0f; validArr[i] = 0;
            } else {
                // s_sum and argmax (first occurrence of max; js ascending + strict >)
                float ssum = 0.0f, smax = -1e30f; int kref = 0;
                for (int k = 0; k < m; ++k) {
                    float sc = ms[k];
                    ssum += sc;
                    if (sc > smax) { smax = sc; kref = k; }
                }
                float refdir = ds[kref];
                float denom = fmaxf(ssum, 1e-12f);
                float sgt = 0.0f;
                float cd0=0,cd1=0,cd2=0,cd3=0,cd4=0,cd5=0;
                for (int k = 0; k < m; ++k) {
                    int j = js[k];
                    float sc = ms[k];
                    float d = fabsf(ds[k] - refdir);
                    if (d > PI_F) d = TWO_PI_F - d;
                    if (d > HALF_PI_F) sgt += sc;
                    float wgt = sc / denom;
                    cd0 += wgt * boxes[j*7+0];
                    cd1 += wgt * boxes[j*7+1];
                    cd2 += wgt * boxes[j*7+2];
                    cd3 += wgt * boxes[j*7+3];
                    cd4 += wgt * boxes[j*7+4];
                    cd5 += wgt * boxes[j*7+5];
                }
                float sle = ssum - sgt;
                bool flipGt = (sgt <= sle);
                float ssin = 0.0f, scos = 0.0f;
                for (int k = 0; k < m; ++k) {
                    float sc = ms[k];
                    float dj = ds[k];
                    float d = fabsf(dj - refdir);
                    if (d > PI_F) d = TWO_PI_F - d;
                    bool gt = d > HALF_PI_F;
                    bool flip = flipGt ? gt : !gt;
                    float adj_d = limit_period_f(dj + (flip ? PI_F : 0.0f));
                    float wgt = sc / denom;
                    ssin += sinf(adj_d) * wgt;
                    scos += cosf(adj_d) * wgt;
                }
                float theta = atan2f(ssin, scos);
                // s_fused: sort member scores descending, sum s_k^(k+1)
                for (int k = 1; k < m; ++k) {
                    float key = ms[k]; int p = k - 1;
                    while (p >= 0 && ms[p] < key) { ms[p+1] = ms[p]; --p; }
                    ms[p+1] = key;
                }
                float sf = 0.0f;
                for (int k = 0; k < m; ++k) sf += powf(ms[k], (float)(k+1));
                sf = fminf(sf, 1.0f);
                // corners range check
                float c_ = cosf(theta), s_ = sinf(theta);
                float wdim = cd4, ldim = cd5;
                const float xs[4]  = {0.5f, 0.5f, -0.5f, -0.5f};
                const float ys_[4] = {-0.5f, 0.5f, 0.5f, -0.5f};
                bool inr = true;
                for (int c = 0; c < 4; ++c) {
                    float cx = ldim * xs[c], cy = wdim * ys_[c];
                    float rx = cx*c_ - cy*s_ + cd0;
                    float ry = cx*s_ + cy*c_ + cd1;
                    inr = inr && (rx > -140.8f) && (rx < 140.8f) && (ry > -40.0f) && (ry < 40.0f);
                }
                fused[i*7+0]=cd0; fused[i*7+1]=cd1; fused[i*7+2]=cd2;
                fused[i*7+3]=cd3; fused[i*7+4]=cd4; fused[i*7+5]=cd5;
                fused[i*7+6]=theta;
                sfused[i] = sf;
                validArr[i] = inr ? 1 : 0;
            }
        }
        __syncthreads();
    }
}

// ---------------- Kernel 4: cumsum + gated output writes ----------------
__global__ void finalize_kernel(const float* __restrict__ fused,
                                const float* __restrict__ sfused,
                                const int* __restrict__ validArr,
                                const int* __restrict__ indices,
                                float* __restrict__ out, int n) {
    __shared__ int newidS[4096];
    __shared__ unsigned char validS[4096];
    __shared__ int scanBuf[1024];
    int tid = threadIdx.x;  // 1024
    int per = (n + 1023) >> 10;  // 4
    int base = tid * per;
    int v[8];
    int sum = 0;
    for (int k = 0; k < per && k < 8; ++k) {
        int j = base + k;
        int vv = (j < n) ? validArr[j] : 0;
        v[k] = vv; sum += vv;
    }
    scanBuf[tid] = sum;
    __syncthreads();
    for (int o = 1; o < 1024; o <<= 1) {
        int val = scanBuf[tid];
        int add = (tid >= o) ? scanBuf[tid - o] : 0;
        __syncthreads();
        scanBuf[tid] = val + add;
        __syncthreads();
    }
    int run = scanBuf[tid] - sum;
    for (int k = 0; k < per && k < 8; ++k) {
        int j = base + k;
        if (j < n) { run += v[k]; newidS[j] = run; validS[j] = (unsigned char)v[k]; }
    }
    __syncthreads();
    float* boxesO  = out;
    float* scoresO = out + (size_t)7*n;
    float* validO  = out + (size_t)8*n;
    float* idxO    = out + (size_t)9*n;
    for (int j = tid; j < n; j += 1024) {
        int vv = validS[j];
        #pragma unroll
        for (int k = 0; k < 7; ++k)
            boxesO[j*7+k] = vv ? fused[j*7+k] : 0.0f;
        scoresO[j] = vv ? sfused[j] : 0.0f;
        validO[j]  = vv ? 1.0f : 0.0f;
        int ind = indices[j];
        int safe = ind - 1; if (safe < 0) safe = 0;
        bool nv = (ind > 0) && (validS[safe] != 0);
        idxO[j] = nv ? (float)newidS[safe] : 0.0f;
    }
}

extern "C" void kernel_launch(void* const* d_in, const int* in_sizes, int n_in,
                              void* d_out, int out_size, void* d_ws, size_t ws_size,
                              hipStream_t stream) {
    const float* boxes  = (const float*)d_in[0];
    const float* scores = (const float*)d_in[1];
    int n = in_sizes[0] / 7;           // 4096
    int words = (n + 63) >> 6;         // 64
    int ngroups = (words + 7) >> 3;    // 8

    char* ws = (char*)d_ws;
    size_t off = 0;
    u64* adjC = (u64*)(ws + off);
    off += (size_t)n * words * sizeof(u64);
    u64* S = (u64*)(ws + off); off += 64 * sizeof(u64);
    int* seedList = (int*)(ws + off); off += (size_t)n * sizeof(int);
    int* indices  = (int*)(ws + off); off += (size_t)n * sizeof(int);
    float* fused  = (float*)(ws + off); off += (size_t)n * 7 * sizeof(float);
    float* sfused = (float*)(ws + off); off += (size_t)n * sizeof(float);
    int* validArr = (int*)(ws + off); off += (size_t)n * sizeof(int);
    int* nclust   = (int*)(ws + off); off += sizeof(int);
    off = (off + 7) & ~(size_t)7;
    // zeroed region: occMask[64] + flag
    u64* occMask = (u64*)(ws + off);
    int* flag    = (int*)(ws + off + 64 * sizeof(u64));
    size_t zbytes = 64 * sizeof(u64) + 8;

    hipMemsetAsync(occMask, 0, zbytes, stream);
    dim3 adjGrid(words, (n + 255) / 256);
    adj_kernel<<<adjGrid, 256, 0, stream>>>(boxes, adjC, occMask, n, words);
    mis_chain_kernel<<<ngroups, 512, 0, stream>>>(adjC, occMask, S, indices, seedList,
                                                  nclust, flag, n, words, ngroups);
    fusion_kernel<<<512, 64, 0, stream>>>(boxes, scores, indices, seedList, nclust,
                                          adjC, fused, sfused, validArr, n, words);
    finalize_kernel<<<1, 1024, 0, stream>>>(fused, sfused, validArr, indices,
                                            (float*)d_out, n);
}

// Round 13
// 174.806 us; speedup vs baseline: 1.1073x; 1.0539x over previous
//
#include <hip/hip_runtime.h>
#include <math.h>

#define PI_F      3.141592653f
#define TWO_PI_F  6.283185306f
#define HALF_PI_F 1.5707963265f
#define IOU_THR_F 0.1f
#define MIS_CAP   180      // LDS slots for upper-triangle tiles (beyond 64 diag)

typedef unsigned long long u64;

__device__ __forceinline__ float limit_period_f(float v) {
    return v - floorf(v / TWO_PI_F + 0.5f) * TWO_PI_F;
}

__device__ __forceinline__ u64 shfl_u64(u64 v, int src) {
    unsigned int lo = (unsigned int)(v & 0xffffffffull);
    unsigned int hi = (unsigned int)(v >> 32);
    lo = __shfl((int)lo, src);
    hi = __shfl((int)hi, src);
    return ((u64)hi << 32) | (u64)lo;
}

// ---------------- Kernel 1: adjacency + occByte (single-producer, no atomics) -
// Thread owns (row i, word w): 64 in-register IoUs vs LDS-staged j-boxes.
// adjC[(size_t)w * n + i] = word w of row i.
// occByte[rb*64 + w] = 1 iff any row in block rb has nonzero word w.
__global__ void adj_kernel(const float* __restrict__ boxes,
                           u64* __restrict__ adjC,
                           unsigned char* __restrict__ occByte,
                           int n, int words) {
    __shared__ float jS[7][64];
    int w = blockIdx.x;
    int tid = threadIdx.x;              // 256 = 4 waves
    int lane = tid & 63, wv = tid >> 6;
    if (tid < 64) {
        int j = (w << 6) + tid;
        if (j < n) {
            float b0 = boxes[j*7+0], b1 = boxes[j*7+1], b2 = boxes[j*7+2];
            float b3 = boxes[j*7+3], b4 = boxes[j*7+4], b5 = boxes[j*7+5];
            jS[0][tid] = b0 - b5*0.5f;  jS[3][tid] = b0 + b5*0.5f;
            jS[1][tid] = b1 - b4*0.5f;  jS[4][tid] = b1 + b4*0.5f;
            jS[2][tid] = b2 - b3*0.5f;  jS[5][tid] = b2 + b3*0.5f;
            jS[6][tid] = (b5*b4)*b3;
        }
    }
    __syncthreads();
    int i = blockIdx.y * 256 + tid;
    u64 word = 0ull;
    if (i < n) {
        float b0 = boxes[i*7+0], b1 = boxes[i*7+1], b2 = boxes[i*7+2];
        float b3 = boxes[i*7+3], b4 = boxes[i*7+4], b5 = boxes[i*7+5];
        float lix = b0 - b5*0.5f, hix = b0 + b5*0.5f;
        float liy = b1 - b4*0.5f, hiy = b1 + b4*0.5f;
        float liz = b2 - b3*0.5f, hiz = b2 + b3*0.5f;
        float vi  = (b5*b4)*b3;
        int jmax = n - (w << 6); if (jmax > 64) jmax = 64;
        for (int jj = 0; jj < jmax; ++jj) {
            float ix = fminf(hix, jS[3][jj]) - fmaxf(lix, jS[0][jj]); ix = fmaxf(ix, 0.0f);
            float iy = fminf(hiy, jS[4][jj]) - fmaxf(liy, jS[1][jj]); iy = fmaxf(iy, 0.0f);
            float iz = fminf(hiz, jS[5][jj]) - fmaxf(liz, jS[2][jj]); iz = fmaxf(iz, 0.0f);
            float inter = (ix*iy)*iz;
            float u = fmaxf(vi + jS[6][jj] - inter, 1e-8f);
            bool pred = (inter / u) > IOU_THR_F;
            word |= ((u64)(pred ? 1 : 0)) << jj;
        }
        adjC[(size_t)w * n + i] = word;
    }
    u64 bal = __ballot((i < n) && word != 0ull);
    int rb = blockIdx.y * 4 + wv;
    if (lane == 0 && rb < 64)
        occByte[rb * 64 + w] = bal ? (unsigned char)1 : (unsigned char)0;
}

// ---------------- Kernel 2: single-WG LDS-tile exact greedy MIS + indices -----
// Occupied tiles (~180 KB measured) fit in LDS: load diag + upper tiles in one
// parallel burst; wave 0 runs the exact 64-word ordered chain purely from
// LDS/registers (eMask push via LDS atomicOr); then all waves compute
// indices/seedList/nclust. Zero inter-block coordination.
__global__ __launch_bounds__(1024) void mis_tile_kernel(
        const u64* __restrict__ adjC,
        const unsigned char* __restrict__ occByte,
        int* __restrict__ indices,
        int* __restrict__ seedList,
        int* __restrict__ nclust,
        int n, int words) {
    extern __shared__ u64 dynbuf[];     // (64 + MIS_CAP) tiles of 64 u64
    __shared__ u64 occL[64];
    __shared__ u64 eMaskL[64];
    __shared__ u64 smS[64];
    __shared__ int wsS[64];
    __shared__ int slotBase[64];
    int tid = threadIdx.x;              // 1024 = 16 waves
    int lane = tid & 63, wv = tid >> 6;

    // occL[rb] from occByte (ballot per 64 bytes)
    for (int rb = wv; rb < 64; rb += 16) {
        unsigned char b = occByte[rb * 64 + lane];
        u64 m = __ballot(b != 0);
        if (lane == 0) occL[rb] = m;
    }
    __syncthreads();
    // slot bases for upper tiles (exclusive scan over upper-bit counts)
    if (tid < 64) {
        eMaskL[tid] = 0ull;
        smS[tid] = 0ull;
        u64 up = (tid < words) ? (occL[tid] & ((tid < 63) ? ~((2ull << tid) - 1ull) : 0ull)) : 0ull;
        int c = (int)__popcll(up);
        int x = c;
        for (int o = 1; o < 64; o <<= 1) {
            int y = __shfl_up(x, o);
            if (tid >= o) x += y;
        }
        slotBase[tid] = 64 + (x - c);
    }
    __syncthreads();
    // burst load: diagonal tiles (slot rb) + upper tiles (slotBase order)
    for (int rb = wv; rb < 64; rb += 16) {
        int i2 = (rb << 6) + lane;
        dynbuf[(size_t)rb * 64 + lane] =
            (rb < words && i2 < n) ? adjC[(size_t)rb * n + i2] : 0ull;
        if (rb < words) {
            u64 up = occL[rb] & ((rb < 63) ? ~((2ull << rb) - 1ull) : 0ull);
            int si = slotBase[rb];
            while (up) {
                int w2 = (int)__ffsll(up) - 1; up &= up - 1;
                if (si < 64 + MIS_CAP)
                    dynbuf[(size_t)si * 64 + lane] = (i2 < n) ? adjC[(size_t)w2 * n + i2] : 0ull;
                ++si;
            }
        }
    }
    __syncthreads();

    // ---- exact ordered chain (wave 0 only; pure LDS/registers) ----
    if (wv == 0) {
        for (int w = 0; w < words && w < 64; ++w) {
            u64 Adiag = dynbuf[(size_t)w * 64 + lane];   // lane's row in diag tile
            u64 em = eMaskL[w];                          // uniform broadcast read
            int base = w << 6;
            int vb = n - base;
            u64 valid = (vb >= 64) ? ~0ull : ((vb <= 0) ? 0ull : ((1ull << vb) - 1ull));
            u64 cand = valid & ~em;
            u64 s = 0ull;
            while (cand) {                 // exact in-word ascending greedy
                int b = (int)__ffsll(cand) - 1;
                s |= 1ull << b;
                u64 Ab = shfl_u64(Adiag, b);
                cand &= ~Ab;
                u64 him = (b >= 63) ? 0ull : ~((2ull << b) - 1ull);
                cand &= him;
            }
            if (lane == 0) smS[w] = s;
            // push: each seed lane ORs its future-row words into eMask
            if ((s >> lane) & 1ull) {
                u64 fut = occL[w] & ((w < 63) ? ~((2ull << w) - 1ull) : 0ull);
                int si = slotBase[w];
                while (fut) {
                    int w2 = (int)__ffsll(fut) - 1; fut &= fut - 1;
                    u64 rowv = (si < 64 + MIS_CAP)
                             ? dynbuf[(size_t)si * 64 + lane]
                             : adjC[(size_t)w2 * n + (base + lane)];
                    if (rowv) atomicOr(&eMaskL[w2], rowv);
                    ++si;
                }
            }
            asm volatile("s_waitcnt lgkmcnt(0) vmcnt(0)" ::: "memory");
        }
    }
    __syncthreads();
    // seed-rank prefix + nclust
    if (tid < 64) {
        int pc = (int)__popcll(smS[tid]);
        int x = pc;
        for (int o = 1; o < 64; o <<= 1) {
            int y = __shfl_up(x, o);
            if (tid >= o) x += y;
        }
        wsS[tid] = x - pc;
        if (tid == 63) *nclust = x;
    }
    __syncthreads();
    // indices[j] = rank of max-index adjacent seed; seedList (all 16 waves)
    for (int j = tid; j < n; j += 1024) {
        int rb = j >> 6;
        int best = -1;
        u64 tmp = occL[rb];
        while (tmp) {
            int w2 = (int)__ffsll(tmp) - 1; tmp &= tmp - 1;
            u64 m = adjC[(size_t)w2 * n + j] & smS[w2];   // coalesced across j
            if (m) best = (w2 << 6) + 63 - (int)__clzll(m);
        }
        int idx = 0;
        if (best >= 0) {
            int w2 = best >> 6, b = best & 63;
            u64 incl = (b >= 63) ? ~0ull : ((2ull << b) - 1ull);
            idx = wsS[w2] + (int)__popcll(smS[w2] & incl);  // 1-based cid
        }
        indices[j] = idx;
        int bj = j & 63;
        if ((smS[rb] >> bj) & 1ull) {
            int rank = wsS[rb] + (int)__popcll(smS[rb] & (bj ? ((1ull << bj) - 1ull) : 0ull)) + 1;
            seedList[rank - 1] = j;
        }
    }
}

// ---------------- Kernel 3: per-cluster fusion (grid-stride, 1 wave/block) ----
__global__ void fusion_kernel(const float* __restrict__ boxes,
                              const float* __restrict__ scores,
                              const int* __restrict__ indices,
                              const int* __restrict__ seedListG,
                              const int* __restrict__ nclust,
                              const u64* __restrict__ adjC,
                              float* __restrict__ fused,
                              float* __restrict__ sfused,
                              int* __restrict__ validArr, int n, int words) {
    int lane = threadIdx.x;       // 64 = 1 wave
    int nc = *nclust;
    __shared__ unsigned short js[256];
    __shared__ float ms[256];
    __shared__ float ds[256];
    for (int i = blockIdx.x; i < n; i += gridDim.x) {
        int cid = i + 1;
        if (cid > nc) {
            if (lane < 7) fused[i*7+lane] = 0.0f;
            if (lane == 0) { sfused[i] = 0.0f; validArr[i] = 0; }
            continue;
        }
        int s = seedListG[i];
        u64 bits = (lane < words) ? adjC[(size_t)lane * n + s] : 0ull;
        // filter: keep only nodes whose final cluster is cid
        u64 keep = 0ull;
        u64 t = bits;
        while (t) {
            int b = (int)__ffsll(t) - 1;
            t &= t - 1;
            int node = (lane << 6) + b;
            if (indices[node] == cid) keep |= (1ull << b);
        }
        int cnt = __popcll(keep);
        int x = cnt;
        for (int o = 1; o < 64; o <<= 1) {
            int y = __shfl_up(x, o);
            if (lane >= o) x += y;
        }
        int excl = x - cnt;
        int m = __shfl(x, 63);
        int pos = excl;
        t = keep;
        while (t) {
            int b = (int)__ffsll(t) - 1;
            t &= t - 1;
            js[pos++] = (unsigned short)((lane << 6) + b);
        }
        __syncthreads();
        for (int k = lane; k < m; k += 64) {
            int j = js[k];
            ms[k] = scores[j];
            ds[k] = limit_period_f(boxes[j*7+6]);
        }
        __syncthreads();
        if (lane == 0) {
            if (m == 0) {
                for (int k = 0; k < 7; ++k) fused[i*7+k] = 0.0f;
                sfused[i] = 0.0f; validArr[i] = 0;
            } else {
                // s_sum and argmax (first occurrence of max; js ascending + strict >)
                float ssum = 0.0f, smax = -1e30f; int kref = 0;
                for (int k = 0; k < m; ++k) {
                    float sc = ms[k];
                    ssum += sc;
                    if (sc > smax) { smax = sc; kref = k; }
                }
                float refdir = ds[kref];
                float denom = fmaxf(ssum, 1e-12f);
                float sgt = 0.0f;
                float cd0=0,cd1=0,cd2=0,cd3=0,cd4=0,cd5=0;
                for (int k = 0; k < m; ++k) {
                    int j = js[k];
                    float sc = ms[k];
                    float d = fabsf(ds[k] - refdir);
                    if (d > PI_F) d = TWO_PI_F - d;
                    if (d > HALF_PI_F) sgt += sc;
                    float wgt = sc / denom;
                    cd0 += wgt * boxes[j*7+0];
                    cd1 += wgt * boxes[j*7+1];
                    cd2 += wgt * boxes[j*7+2];
                    cd3 += wgt * boxes[j*7+3];
                    cd4 += wgt * boxes[j*7+4];
                    cd5 += wgt * boxes[j*7+5];
                }
                float sle = ssum - sgt;
                bool flipGt = (sgt <= sle);
                float ssin = 0.0f, scos = 0.0f;
                for (int k = 0; k < m; ++k) {
                    float sc = ms[k];
                    float dj = ds[k];
                    float d = fabsf(dj - refdir);
                    if (d > PI_F) d = TWO_PI_F - d;
                    bool gt = d > HALF_PI_F;
                    bool flip = flipGt ? gt : !gt;
                    float adj_d = limit_period_f(dj + (flip ? PI_F : 0.0f));
                    float wgt = sc / denom;
                    ssin += sinf(adj_d) * wgt;
                    scos += cosf(adj_d) * wgt;
                }
                float theta = atan2f(ssin, scos);
                // s_fused: sort member scores descending, sum s_k^(k+1)
                for (int k = 1; k < m; ++k) {
                    float key = ms[k]; int p = k - 1;
                    while (p >= 0 && ms[p] < key) { ms[p+1] = ms[p]; --p; }
                    ms[p+1] = key;
                }
                float sf = 0.0f;
                for (int k = 0; k < m; ++k) sf += powf(ms[k], (float)(k+1));
                sf = fminf(sf, 1.0f);
                // corners range check
                float c_ = cosf(theta), s_ = sinf(theta);
                float wdim = cd4, ldim = cd5;
                const float xs[4]  = {0.5f, 0.5f, -0.5f, -0.5f};
                const float ys_[4] = {-0.5f, 0.5f, 0.5f, -0.5f};
                bool inr = true;
                for (int c = 0; c < 4; ++c) {
                    float cx = ldim * xs[c], cy = wdim * ys_[c];
                    float rx = cx*c_ - cy*s_ + cd0;
                    float ry = cx*s_ + cy*c_ + cd1;
                    inr = inr && (rx > -140.8f) && (rx < 140.8f) && (ry > -40.0f) && (ry < 40.0f);
                }
                fused[i*7+0]=cd0; fused[i*7+1]=cd1; fused[i*7+2]=cd2;
                fused[i*7+3]=cd3; fused[i*7+4]=cd4; fused[i*7+5]=cd5;
                fused[i*7+6]=theta;
                sfused[i] = sf;
                validArr[i] = inr ? 1 : 0;
            }
        }
        __syncthreads();
    }
}

// ---------------- Kernel 4: cumsum + gated output writes ----------------
__global__ void finalize_kernel(const float* __restrict__ fused,
                                const float* __restrict__ sfused,
                                const int* __restrict__ validArr,
                                const int* __restrict__ indices,
                                float* __restrict__ out, int n) {
    __shared__ int newidS[4096];
    __shared__ unsigned char validS[4096];
    __shared__ int scanBuf[1024];
    int tid = threadIdx.x;  // 1024
    int per = (n + 1023) >> 10;  // 4
    int base = tid * per;
    int v[8];
    int sum = 0;
    for (int k = 0; k < per && k < 8; ++k) {
        int j = base + k;
        int vv = (j < n) ? validArr[j] : 0;
        v[k] = vv; sum += vv;
    }
    scanBuf[tid] = sum;
    __syncthreads();
    for (int o = 1; o < 1024; o <<= 1) {
        int val = scanBuf[tid];
        int add = (tid >= o) ? scanBuf[tid - o] : 0;
        __syncthreads();
        scanBuf[tid] = val + add;
        __syncthreads();
    }
    int run = scanBuf[tid] - sum;
    for (int k = 0; k < per && k < 8; ++k) {
        int j = base + k;
        if (j < n) { run += v[k]; newidS[j] = run; validS[j] = (unsigned char)v[k]; }
    }
    __syncthreads();
    float* boxesO  = out;
    float* scoresO = out + (size_t)7*n;
    float* validO  = out + (size_t)8*n;
    float* idxO    = out + (size_t)9*n;
    for (int j = tid; j < n; j += 1024) {
        int vv = validS[j];
        #pragma unroll
        for (int k = 0; k < 7; ++k)
            boxesO[j*7+k] = vv ? fused[j*7+k] : 0.0f;
        scoresO[j] = vv ? sfused[j] : 0.0f;
        validO[j]  = vv ? 1.0f : 0.0f;
        int ind = indices[j];
        int safe = ind - 1; if (safe < 0) safe = 0;
        bool nv = (ind > 0) && (validS[safe] != 0);
        idxO[j] = nv ? (float)newidS[safe] : 0.0f;
    }
}

extern "C" void kernel_launch(void* const* d_in, const int* in_sizes, int n_in,
                              void* d_out, int out_size, void* d_ws, size_t ws_size,
                              hipStream_t stream) {
    const float* boxes  = (const float*)d_in[0];
    const float* scores = (const float*)d_in[1];
    int n = in_sizes[0] / 7;           // 4096
    int words = (n + 63) >> 6;         // 64

    char* ws = (char*)d_ws;
    size_t off = 0;
    u64* adjC = (u64*)(ws + off);
    off += (size_t)n * words * sizeof(u64);
    unsigned char* occByte = (unsigned char*)(ws + off); off += 64 * 64;
    int* seedList = (int*)(ws + off); off += (size_t)n * sizeof(int);
    int* indices  = (int*)(ws + off); off += (size_t)n * sizeof(int);
    float* fused  = (float*)(ws + off); off += (size_t)n * 7 * sizeof(float);
    float* sfused = (float*)(ws + off); off += (size_t)n * sizeof(float);
    int* validArr = (int*)(ws + off); off += (size_t)n * sizeof(int);
    int* nclust   = (int*)(ws + off); off += sizeof(int);

    dim3 adjGrid(words, (n + 255) / 256);
    adj_kernel<<<adjGrid, 256, 0, stream>>>(boxes, adjC, occByte, n, words);
    size_t misLds = (size_t)(64 + MIS_CAP) * 64 * sizeof(u64);   // ~125 KB
    mis_tile_kernel<<<1, 1024, misLds, stream>>>(adjC, occByte, indices, seedList,
                                                 nclust, n, words);
    fusion_kernel<<<512, 64, 0, stream>>>(boxes, scores, indices, seedList, nclust,
                                          adjC, fused, sfused, validArr, n, words);
    finalize_kernel<<<1, 1024, 0, stream>>>(fused, sfused, validArr, indices,
                                            (float*)d_out, n);
}